// Round 8
// baseline (179.660 us; speedup 1.0000x reference)
//
#include <hip/hip_runtime.h>
#include <hip/hip_cooperative_groups.h>
#include <math.h>

namespace cg = cooperative_groups;

#define HH 496
#define WW 496
#define HWSZ (HH*WW)
#define NW 31
#define NWIN (NW*NW)   // 961

__constant__ float c_thetas[8] = {
    0.39269908169872414f, 0.7853981633974483f, 1.1780972450961724f,
    1.5707963267948966f,  1.9634954084936207f, 2.356194490192345f,
    2.748893571891069f,   3.141592653589793f};

// ---- Kernel 1: Gabor bank TRANSPOSED as filt[k][f] (k=0..24, f=c*8+t) + zero meanacc ----
__global__ void bank_kernel(const float* __restrict__ sigmas,
                            const float* __restrict__ lambdas,
                            float* __restrict__ filt,
                            float* __restrict__ meanacc) {
    int idx = threadIdx.x + blockIdx.x * blockDim.x;
    if (idx >= 1800) {
        if (idx < 1809) meanacc[(idx - 1800) * 16] = 0.0f;  // one per 64B line
        return;
    }
    int f = idx / 25, k = idx % 25;
    int dy = k / 5, dx = k % 5;
    int s = f / 24, rem = f % 24, l = rem / 8, t = rem % 8;
    float sig = sigmas[s], lam = lambdas[l], th = c_thetas[t];
    float y = (float)dy - 2.0f, x = (float)dx - 2.0f;
    float st = sinf(th), ct = cosf(th);
    float yt = -x * st + y * ct;
    float xt =  x * ct + y * st;
    float sx2 = sig * sig;          // sigma_x = sig
    float sy2 = 4.0f * sig * sig;   // sigma_y = sig/0.5
    float g = expf(-0.5f * (xt * xt / sx2 + yt * yt / sy2)) *
              cosf(6.28318530717958647692f * xt / lam + 1.5707963267948966f);
    filt[k * 72 + f] = g;           // transposed layout
}

// named accumulators -- arrays get demoted to scratch (VGPR=28 evidence, R6)
#define FMAS(FP, P) \
    a0  = fmaf(P, (FP)[0],  a0);  a1  = fmaf(P, (FP)[1],  a1);  \
    a2  = fmaf(P, (FP)[2],  a2);  a3  = fmaf(P, (FP)[3],  a3);  \
    a4  = fmaf(P, (FP)[4],  a4);  a5  = fmaf(P, (FP)[5],  a5);  \
    a6  = fmaf(P, (FP)[6],  a6);  a7  = fmaf(P, (FP)[7],  a7);  \
    a8  = fmaf(P, (FP)[8],  a8);  a9  = fmaf(P, (FP)[9],  a9);  \
    a10 = fmaf(P, (FP)[10], a10); a11 = fmaf(P, (FP)[11], a11); \
    a12 = fmaf(P, (FP)[12], a12); a13 = fmaf(P, (FP)[13], a13); \
    a14 = fmaf(P, (FP)[14], a14); a15 = fmaf(P, (FP)[15], a15); \
    a16 = fmaf(P, (FP)[16], a16); a17 = fmaf(P, (FP)[17], a17); \
    a18 = fmaf(P, (FP)[18], a18); a19 = fmaf(P, (FP)[19], a19); \
    a20 = fmaf(P, (FP)[20], a20); a21 = fmaf(P, (FP)[21], a21); \
    a22 = fmaf(P, (FP)[22], a22); a23 = fmaf(P, (FP)[23], a23);

#define STEP(K, DY, DX) { \
    float pix = mytile[tbase + (DY)*20 + (DX)]; \
    const float* fp = fbase + (K)*72; \
    FMAS(fp, pix) }

#define MAX8(B) fmaxf(fmaxf(fmaxf(a##B,a1##B... )))  /* unused placeholder */

// one channel group (24 filters -> 3 channel maxima into CS0..CS2)
#define CONV_GROUP(CG, CS0, CS1, CS2) { \
    float a0=0,a1=0,a2=0,a3=0,a4=0,a5=0,a6=0,a7=0,a8=0,a9=0,a10=0,a11=0, \
          a12=0,a13=0,a14=0,a15=0,a16=0,a17=0,a18=0,a19=0,a20=0,a21=0,a22=0,a23=0; \
    const float* fbase = filt + (CG)*24; \
    STEP( 0,0,0) STEP( 1,0,1) STEP( 2,0,2) STEP( 3,0,3) STEP( 4,0,4) \
    STEP( 5,1,0) STEP( 6,1,1) STEP( 7,1,2) STEP( 8,1,3) STEP( 9,1,4) \
    STEP(10,2,0) STEP(11,2,1) STEP(12,2,2) STEP(13,2,3) STEP(14,2,4) \
    STEP(15,3,0) STEP(16,3,1) STEP(17,3,2) STEP(18,3,3) STEP(19,3,4) \
    STEP(20,4,0) STEP(21,4,1) STEP(22,4,2) STEP(23,4,3) STEP(24,4,4) \
    CS0 = fmaxf(fmaxf(fmaxf(a0,a1),fmaxf(a2,a3)),fmaxf(fmaxf(a4,a5),fmaxf(a6,a7))); \
    CS1 = fmaxf(fmaxf(fmaxf(a8,a9),fmaxf(a10,a11)),fmaxf(fmaxf(a12,a13),fmaxf(a14,a15))); \
    CS2 = fmaxf(fmaxf(fmaxf(a16,a17),fmaxf(a18,a19)),fmaxf(fmaxf(a20,a21),fmaxf(a22,a23))); \
    if (active) { \
        out[((CG)*3+0)*HWSZ + y*WW + x] = CS0; \
        out[((CG)*3+1)*HWSZ + y*WW + x] = CS1; \
        out[((CG)*3+2)*HWSZ + y*WW + x] = CS2; } }

#define REDC(C, V) { \
        float s = V; \
        s += __shfl_down(s, 32, 64); s += __shfl_down(s, 16, 64); \
        s += __shfl_down(s,  8, 64); s += __shfl_down(s,  4, 64); \
        s += __shfl_down(s,  2, 64); s += __shfl_down(s,  1, 64); \
        if ((threadIdx.x & 63) == 0) red[threadIdx.x >> 6][C] = s; }

// ---- Kernel 2 (cooperative): 512 thr = 2 windows/block; conv -> grid.sync -> patch ----
__global__ __launch_bounds__(512, 4) void fused_kernel(
    const float* __restrict__ img, const float* __restrict__ filt,
    float* __restrict__ out, float* meanacc, float* __restrict__ dst) {
    __shared__ float tile[2][400];
    __shared__ float red[8][9];
    __shared__ int lds_and[8];
    __shared__ int lds_or[8];

    cg::grid_group grid = cg::this_grid();

    int half = threadIdx.x >> 8;        // 0/1: which window of the pair
    int tid  = threadIdx.x & 255;
    int pair = blockIdx.x;              // 0..495
    int by = pair >> 4;                 // 0..30
    int bx = (pair & 15) * 2 + half;    // 0..31
    bool active = (bx < NW);
    int tx = tid & 15, ty = tid >> 4;

    // ---------- Phase 1: conv ----------
    float* mytile = tile[half];
    for (int i = tid; i < 400; i += 256) {
        int tY = i / 20, tX = i % 20;
        int gy = by * 16 + tY - 2, gx = bx * 16 + tX - 2;
        float v = 0.0f;
        if (gy >= 0 && gy < HH && gx >= 0 && gx < WW) v = img[gy * WW + gx];
        mytile[i] = v;
    }
    __syncthreads();

    int tbase = ty * 20 + tx;
    int y = by * 16 + ty, x = bx * 16 + tx;

    float cs0, cs1, cs2, cs3, cs4, cs5, cs6, cs7, cs8;
    CONV_GROUP(0, cs0, cs1, cs2)
    CONV_GROUP(1, cs3, cs4, cs5)
    CONV_GROUP(2, cs6, cs7, cs8)

    REDC(0, cs0) REDC(1, cs1) REDC(2, cs2) REDC(3, cs3) REDC(4, cs4)
    REDC(5, cs5) REDC(6, cs6) REDC(7, cs7) REDC(8, cs8)
    __syncthreads();
    if (active && tid < 9) {
        int h4 = half * 4;
        atomicAdd(&meanacc[tid * 16],
                  red[h4][tid] + red[h4+1][tid] + red[h4+2][tid] + red[h4+3][tid]);
    }

    // ---------- grid-wide barrier ----------
    grid.sync();

    // ---------- Phase 2: per-window validity + 9-channel patch copy ----------
    int r = by, cl = bx;
    int wy = tid >> 4, wx = tid & 15;
    int rowbase = (r * 16 + wy) * WW + cl * 16 + wx;
    int cbase   = (r * 16 + 8) * WW + cl * 16;       // flat idx 128 = (8,0)

    volatile float* mv = meanacc;   // updated by atomics this kernel: no s_load caching
    int okmask = 0;
#pragma unroll
    for (int c = 0; c < 9; c++) {
        float m5 = mv[c * 16] * (5.0f / (float)HWSZ);
        float v  = out[c * HWSZ + rowbase];
        float vc = out[c * HWSZ + cbase];
        float thr  = (v  > m5) ? v  : 0.0f;
        float thrc = (vc > m5) ? vc : 0.0f;
        // first-occurrence argmax: earlier strictly less, later (incl. center) <=
        bool ok = (tid < 128) ? (thr < thrc) : (thr <= thrc);
        okmask |= (ok ? 1 : 0) << c;
    }
#pragma unroll
    for (int off = 1; off < 64; off <<= 1) okmask &= __shfl_xor(okmask, off, 64);
    if ((threadIdx.x & 63) == 0) lds_and[threadIdx.x >> 6] = okmask;

    int i = tid >> 3;            // patch row 0..31
    int jg = (tid & 7) << 2;     // patch col group 0,4,...,28
    int row = r * 16 + i - 8;
    int col = cl * 16 + jg - 8;
    // 4-aligned col groups never straddle the [0,496) edge (496 % 4 == 0)
    bool inb = (row >= 0 && row < HH && col >= 0 && col + 3 < WW) && active;
    size_t pbase = (size_t)row * WW + col;
    int nzmask = 0;
    float4 p0, p1, p2, p3, p4, p5, p6, p7, p8;
#define LOADP(C, V) { \
        V = make_float4(0.f, 0.f, 0.f, 0.f); \
        if (inb) V = *(const float4*)(out + (size_t)(C) * HWSZ + pbase); \
        if (V.x != 0.f || V.y != 0.f || V.z != 0.f || V.w != 0.f) nzmask |= 1 << (C); }
    LOADP(0,p0) LOADP(1,p1) LOADP(2,p2) LOADP(3,p3) LOADP(4,p4)
    LOADP(5,p5) LOADP(6,p6) LOADP(7,p7) LOADP(8,p8)

#pragma unroll
    for (int off = 1; off < 64; off <<= 1) nzmask |= __shfl_xor(nzmask, off, 64);
    if ((threadIdx.x & 63) == 0) lds_or[threadIdx.x >> 6] = nzmask;
    __syncthreads();

    if (active) {
        int h4 = half * 4;
        int am = lds_and[h4] & lds_and[h4+1] & lds_and[h4+2] & lds_and[h4+3];
        int om = lds_or[h4] | lds_or[h4+1] | lds_or[h4+2] | lds_or[h4+3];
        bool valid = (am != 0);
        int w = by * NW + bx;
        size_t dbase = (size_t)w * 1024 + i * 32 + jg;
#define STOREP(C, V) { \
        float mk = (valid && ((om >> (C)) & 1)) ? 1.0f : 0.0f; \
        V.x *= mk; V.y *= mk; V.z *= mk; V.w *= mk; \
        *(float4*)(dst + (size_t)(C) * NWIN * 1024 + dbase) = V; }
        STOREP(0,p0) STOREP(1,p1) STOREP(2,p2) STOREP(3,p3) STOREP(4,p4)
        STOREP(5,p5) STOREP(6,p6) STOREP(7,p7) STOREP(8,p8)
    }
}

extern "C" void kernel_launch(void* const* d_in, const int* in_sizes, int n_in,
                              void* d_out, int out_size, void* d_ws, size_t ws_size,
                              hipStream_t stream) {
    const float* img     = (const float*)d_in[0];
    const float* sigmas  = (const float*)d_in[1];
    const float* lambdas = (const float*)d_in[2];
    float* ws = (float*)d_ws;
    // ws layout (floats): filt[1800] @0, meanacc[144] @2048, out @4096
    float* filt    = ws;
    float* meanacc = ws + 2048;
    float* outb    = ws + 4096;   // 9*496*496 = 2,214,144 floats
    float* dst     = (float*)d_out;

    bank_kernel<<<8, 256, 0, stream>>>(sigmas, lambdas, filt, meanacc);

    void* args[] = {(void*)&img, (void*)&filt, (void*)&outb, (void*)&meanacc, (void*)&dst};
    hipLaunchCooperativeKernel((const void*)fused_kernel, dim3(496), dim3(512),
                               args, 0, stream);
}

// Round 10
// 121.324 us; speedup vs baseline: 1.4808x; 1.4808x over previous
//
#include <hip/hip_runtime.h>
#include <math.h>

#define HH 496
#define WW 496
#define HWSZ (HH*WW)
#define NW 31
#define NWIN (NW*NW)   // 961

typedef float nf4 __attribute__((ext_vector_type(4)));  // native vec for nontemporal builtin

__constant__ float c_thetas[8] = {
    0.39269908169872414f, 0.7853981633974483f, 1.1780972450961724f,
    1.5707963267948966f,  1.9634954084936207f, 2.356194490192345f,
    2.748893571891069f,   3.141592653589793f};

// ---- Kernel 1: Gabor bank TRANSPOSED as filt[k][f] (k=0..24, f=c*8+t) + zero meanacc ----
__global__ void bank_kernel(const float* __restrict__ sigmas,
                            const float* __restrict__ lambdas,
                            float* __restrict__ filt,
                            float* __restrict__ meanacc) {
    int idx = threadIdx.x + blockIdx.x * blockDim.x;
    if (idx >= 1800) {
        if (idx < 1809) meanacc[(idx - 1800) * 16] = 0.0f;  // one per 64B line
        return;
    }
    int f = idx / 25, k = idx % 25;
    int dy = k / 5, dx = k % 5;
    int s = f / 24, rem = f % 24, l = rem / 8, t = rem % 8;
    float sig = sigmas[s], lam = lambdas[l], th = c_thetas[t];
    float y = (float)dy - 2.0f, x = (float)dx - 2.0f;
    float st = sinf(th), ct = cosf(th);
    float yt = -x * st + y * ct;
    float xt =  x * ct + y * st;
    float sx2 = sig * sig;          // sigma_x = sig
    float sy2 = 4.0f * sig * sig;   // sigma_y = sig/0.5
    float g = expf(-0.5f * (xt * xt / sx2 + yt * yt / sy2)) *
              cosf(6.28318530717958647692f * xt / lam + 1.5707963267948966f);
    filt[k * 72 + f] = g;           // transposed layout
}

// named accumulators -- arrays get demoted to scratch (VGPR=28 evidence, R6)
#define FMAS(FP, P) \
    a0  = fmaf(P, (FP)[0],  a0);  a1  = fmaf(P, (FP)[1],  a1);  \
    a2  = fmaf(P, (FP)[2],  a2);  a3  = fmaf(P, (FP)[3],  a3);  \
    a4  = fmaf(P, (FP)[4],  a4);  a5  = fmaf(P, (FP)[5],  a5);  \
    a6  = fmaf(P, (FP)[6],  a6);  a7  = fmaf(P, (FP)[7],  a7);  \
    a8  = fmaf(P, (FP)[8],  a8);  a9  = fmaf(P, (FP)[9],  a9);  \
    a10 = fmaf(P, (FP)[10], a10); a11 = fmaf(P, (FP)[11], a11); \
    a12 = fmaf(P, (FP)[12], a12); a13 = fmaf(P, (FP)[13], a13); \
    a14 = fmaf(P, (FP)[14], a14); a15 = fmaf(P, (FP)[15], a15); \
    a16 = fmaf(P, (FP)[16], a16); a17 = fmaf(P, (FP)[17], a17); \
    a18 = fmaf(P, (FP)[18], a18); a19 = fmaf(P, (FP)[19], a19); \
    a20 = fmaf(P, (FP)[20], a20); a21 = fmaf(P, (FP)[21], a21); \
    a22 = fmaf(P, (FP)[22], a22); a23 = fmaf(P, (FP)[23], a23);

// pixels held in named registers p0..p24 (one ds_read each, reused by all 24 FMAs)
#define STEP(K) { const float* fp = fbase + (K)*72; FMAS(fp, p##K) }

#define ALLSTEPS \
    STEP(0)  STEP(1)  STEP(2)  STEP(3)  STEP(4)  \
    STEP(5)  STEP(6)  STEP(7)  STEP(8)  STEP(9)  \
    STEP(10) STEP(11) STEP(12) STEP(13) STEP(14) \
    STEP(15) STEP(16) STEP(17) STEP(18) STEP(19) \
    STEP(20) STEP(21) STEP(22) STEP(23) STEP(24)

// ---- Kernel 2: conv, channel-split: block z does channels [3z, 3z+3) = 24 filters ----
__global__ __launch_bounds__(256) void conv_kernel(
    const float* __restrict__ img, const float* __restrict__ filt,
    float* __restrict__ out, float* __restrict__ meanacc) {
    __shared__ float tile[20 * 20];
    __shared__ float red[4][3];
    int tid = threadIdx.x;
    int tx = tid & 15, ty = tid >> 4;
    int bx = blockIdx.x, by = blockIdx.y, cg = blockIdx.z;  // channel group

    for (int i = tid; i < 400; i += 256) {
        int tY = i / 20, tX = i % 20;
        int gy = by * 16 + tY - 2, gx = bx * 16 + tX - 2;
        float v = 0.0f;
        if (gy >= 0 && gy < HH && gx >= 0 && gx < WW) v = img[gy * WW + gx];
        tile[i] = v;
    }
    __syncthreads();

    int tbase = ty * 20 + tx;
    // hoist the 25 pixel loads into named registers (exactly 25 ds_read_b32)
    float p0  = tile[tbase +  0], p1  = tile[tbase +  1], p2  = tile[tbase +  2],
          p3  = tile[tbase +  3], p4  = tile[tbase +  4];
    float p5  = tile[tbase + 20], p6  = tile[tbase + 21], p7  = tile[tbase + 22],
          p8  = tile[tbase + 23], p9  = tile[tbase + 24];
    float p10 = tile[tbase + 40], p11 = tile[tbase + 41], p12 = tile[tbase + 42],
          p13 = tile[tbase + 43], p14 = tile[tbase + 44];
    float p15 = tile[tbase + 60], p16 = tile[tbase + 61], p17 = tile[tbase + 62],
          p18 = tile[tbase + 63], p19 = tile[tbase + 64];
    float p20 = tile[tbase + 80], p21 = tile[tbase + 81], p22 = tile[tbase + 82],
          p23 = tile[tbase + 83], p24 = tile[tbase + 84];

    float a0=0,a1=0,a2=0,a3=0,a4=0,a5=0,a6=0,a7=0,a8=0,a9=0,a10=0,a11=0,
          a12=0,a13=0,a14=0,a15=0,a16=0,a17=0,a18=0,a19=0,a20=0,a21=0,a22=0,a23=0;
    const float* fbase = filt + cg * 24;

    ALLSTEPS

    int y = by * 16 + ty, x = bx * 16 + tx;

    float m0 = fmaxf(fmaxf(fmaxf(a0,a1),fmaxf(a2,a3)),fmaxf(fmaxf(a4,a5),fmaxf(a6,a7)));
    float m1 = fmaxf(fmaxf(fmaxf(a8,a9),fmaxf(a10,a11)),fmaxf(fmaxf(a12,a13),fmaxf(a14,a15)));
    float m2 = fmaxf(fmaxf(fmaxf(a16,a17),fmaxf(a18,a19)),fmaxf(fmaxf(a20,a21),fmaxf(a22,a23)));

    out[(cg * 3 + 0) * HWSZ + y * WW + x] = m0;
    out[(cg * 3 + 1) * HWSZ + y * WW + x] = m1;
    out[(cg * 3 + 2) * HWSZ + y * WW + x] = m2;

#define RED(CC, MV) { \
        float s = MV; \
        s += __shfl_down(s, 32, 64); s += __shfl_down(s, 16, 64); \
        s += __shfl_down(s,  8, 64); s += __shfl_down(s,  4, 64); \
        s += __shfl_down(s,  2, 64); s += __shfl_down(s,  1, 64); \
        if ((tid & 63) == 0) red[tid >> 6][CC] = s; }
    RED(0, m0) RED(1, m1) RED(2, m2)
    __syncthreads();
    if (tid < 3)
        atomicAdd(&meanacc[(cg * 3 + tid) * 16],
                  red[0][tid] + red[1][tid] + red[2][tid] + red[3][tid]);
}

// ---- Kernel 3: fused per-window validity + 9-channel patch copy ----
__global__ __launch_bounds__(256) void patch_kernel(
    const float* __restrict__ out, const float* __restrict__ meanacc,
    float* __restrict__ dst) {
    int w = blockIdx.x;
    int r = w / NW, cl = w % NW;
    int tid = threadIdx.x;
    __shared__ int lds_and[4];
    __shared__ int lds_or[4];

    // Stage 1: per-channel "argmax of thresholded window == 128" bit, AND over threads
    int wy = tid >> 4, wx = tid & 15;
    int rowbase = (r * 16 + wy) * WW + cl * 16 + wx;
    int cbase   = (r * 16 + 8) * WW + cl * 16;       // flat idx 128 = (8,0)
    int okmask = 0;
#pragma unroll
    for (int c = 0; c < 9; c++) {
        float m5 = meanacc[c * 16] * (5.0f / (float)HWSZ);
        float v  = out[c * HWSZ + rowbase];
        float vc = out[c * HWSZ + cbase];
        float thr  = (v  > m5) ? v  : 0.0f;
        float thrc = (vc > m5) ? vc : 0.0f;
        // first-occurrence argmax: earlier strictly less, later (incl. center) <=
        bool ok = (tid < 128) ? (thr < thrc) : (thr <= thrc);
        okmask |= (ok ? 1 : 0) << c;
    }
#pragma unroll
    for (int off = 1; off < 64; off <<= 1) okmask &= __shfl_xor(okmask, off, 64);
    if ((tid & 63) == 0) lds_and[tid >> 6] = okmask;

    // Stage 2: one float4 per (thread, channel) in NAMED registers; nz bitmask
    int i = tid >> 3;            // patch row 0..31
    int jg = (tid & 7) << 2;     // patch col group 0,4,...,28
    int row = r * 16 + i - 8;
    int col = cl * 16 + jg - 8;
    // 4-aligned col groups never straddle the [0,496) edge (496 % 4 == 0)
    bool inb = (row >= 0 && row < HH && col >= 0 && col + 3 < WW);
    size_t pbase = (size_t)row * WW + col;
    int nzmask = 0;
    nf4 p0, p1, p2, p3, p4, p5, p6, p7, p8;
#define LOADP(C, V) { \
        V = (nf4){0.f, 0.f, 0.f, 0.f}; \
        if (inb) V = *(const nf4*)(out + (size_t)(C) * HWSZ + pbase); \
        if (V.x != 0.f || V.y != 0.f || V.z != 0.f || V.w != 0.f) nzmask |= 1 << (C); }
    LOADP(0,p0) LOADP(1,p1) LOADP(2,p2) LOADP(3,p3) LOADP(4,p4)
    LOADP(5,p5) LOADP(6,p6) LOADP(7,p7) LOADP(8,p8)

#pragma unroll
    for (int off = 1; off < 64; off <<= 1) nzmask |= __shfl_xor(nzmask, off, 64);
    if ((tid & 63) == 0) lds_or[tid >> 6] = nzmask;
    __syncthreads();

    int am = lds_and[0] & lds_and[1] & lds_and[2] & lds_and[3];
    int om = lds_or[0] | lds_or[1] | lds_or[2] | lds_or[3];
    bool valid = (am != 0);

    size_t dbase = (size_t)w * 1024 + i * 32 + jg;
    // nontemporal: dst is streaming (35.4 MB, never re-read) -- keep `out` in L2
#define STOREP(C, V) { \
        float mk = (valid && ((om >> (C)) & 1)) ? 1.0f : 0.0f; \
        V *= mk; \
        __builtin_nontemporal_store(V, (nf4*)(dst + (size_t)(C) * NWIN * 1024 + dbase)); }
    STOREP(0,p0) STOREP(1,p1) STOREP(2,p2) STOREP(3,p3) STOREP(4,p4)
    STOREP(5,p5) STOREP(6,p6) STOREP(7,p7) STOREP(8,p8)
}

extern "C" void kernel_launch(void* const* d_in, const int* in_sizes, int n_in,
                              void* d_out, int out_size, void* d_ws, size_t ws_size,
                              hipStream_t stream) {
    const float* img     = (const float*)d_in[0];
    const float* sigmas  = (const float*)d_in[1];
    const float* lambdas = (const float*)d_in[2];
    float* ws = (float*)d_ws;
    // ws layout (floats): filt[1800] @0, meanacc[144] @2048, out @4096
    float* filt    = ws;
    float* meanacc = ws + 2048;
    float* outb    = ws + 4096;   // 9*496*496 = 2,214,144 floats

    bank_kernel<<<8, 256, 0, stream>>>(sigmas, lambdas, filt, meanacc);
    conv_kernel<<<dim3(NW, NW, 3), 256, 0, stream>>>(img, filt, outb, meanacc);
    patch_kernel<<<NWIN, 256, 0, stream>>>(outb, meanacc, (float*)d_out);
}